// Round 9
// baseline (244.253 us; speedup 1.0000x reference)
//
#include <hip/hip_runtime.h>

// x: (64, 4, 2, 256, 256) f32 ; tensors: (4,4,128,128,2,2,2,2,2) f32 ;
// bias: (4,128,128,2) f32 ; out: (64,4,2,128,128) f32
// sx=sy=256 even -> ix1=2x+1, iy1=2y+1 (clamp inert).
#define NUMN 64
#define CIN 4
#define COUT 4
#define SX 256
#define SY 256
#define NXX 128
#define NYY 128
#define NSPLIT 2
#define NPER (NUMN / NSPLIT)
#define PLANE (SX * SY)
#define SLOTF 4096                   // floats per ring slot: 16 rows x 256

// R13: FETCH-GRANULARITY rewrite. Eight experiments triangulate the binder:
// R4/R8/R11/R12 (4 different structures, occupancy 25-38%, prefetch collapsed
// or uncollapsible, barriers or none) ALL move ~140MB at ~1.6 TB/s in ~86us
// with VALUBusy pinned ~29%. 1.6 TB/s = 2.7 B/cy/CU -- not a CU-edge limit;
// it's DRAM efficiency under 64-256B scattered requests (every variant read x
// as 16 row-slivers per KB, 1KB-strided rows, ~4096 interleaved streams).
// Fix: block = (xi, ALL 128 y, 8 po) = 1024 threads / 16 waves. Per n it
// needs exactly 16 FULL 1KB rows (8 planes x rows {2xi,2xi+1}) = 16KB in
// 2KB-contiguous pairs. Each wave stages ONE full row with ONE gl_lds
// (lane l reads row+16l: sequential 1KB; dest linear = HW constraint).
// Cross-wave sharing -> barrier, in the R8-validated cheap form: per-wave
// counted vmcnt (ladder 2/3/4/5) BEFORE raw s_barrier; STAGE placed AFTER
// the barrier so its target slot (n-1)&3 is provably consumed by all waves
// (program order: compute(n-1) precedes barrier(n) in every wave).
// Loads stay in flight across barriers; vmcnt never drains to 0 in-loop.
__global__ __launch_bounds__(1024, 4)
void ttn_kernel(const float* __restrict__ x, const float* __restrict__ w,
                const float* __restrict__ bias, float* __restrict__ out)
{
    __shared__ float lds[4 * SLOTF];             // 4-slot ring, 64 KB

    const int bid = blockIdx.x;
    const int xi = bid % NXX;
    const int ns = bid / NXX;                    // 0..NSPLIT-1

    const int tid = threadIdx.x;                 // 0..1023
    const int wv  = tid >> 6;                    // wave 0..15 == row R it stages
    const int l   = tid & 63;
    const int po  = tid >> 7;                    // 0..7
    const int p   = po >> 1;
    const int o   = po & 1;
    const int y   = tid & 127;                   // 0..127 (full NYY)

    // ---- weight preamble: wr[c][q], q = 8i+4j+2k+l (float4 loads) ----
    float wr[CIN][16];
#pragma unroll
    for (int c = 0; c < CIN; ++c) {
        const float4* wp4 = (const float4*)(w +
            ((size_t)(((c * COUT + p) * NXX + xi) * NYY + y)) * 32);
#pragma unroll
        for (int j = 0; j < 8; ++j) {
            const float4 v = wp4[j];
            wr[c][2 * j]     = o ? v.y : v.x;
            wr[c][2 * j + 1] = o ? v.w : v.z;
        }
    }
    const float bv = bias[(((p * NXX + xi) * NYY + y) * 2) + o];

    const size_t nstr = (size_t)CIN * 2 * PLANE;
    const size_t ostr = (size_t)COUT * 2 * NXX * NYY;

    // staging: wave wv stages row R=wv = (c*2+d)*2 + r: plane cd=wv>>1,
    // x-row 2xi+(wv&1), ALL 256 cols. lane l reads floats 4l..4l+3 (16B),
    // so the wave's 64 lanes read one sequential 1KB row.
    const float* xs = x + (size_t)(ns * NPER) * nstr
                        + (size_t)(wv >> 1) * PLANE
                        + (size_t)(2 * xi + (wv & 1)) * SY + 4 * l;
    float* ob = out + (size_t)(ns * NPER) * ostr
                    + (size_t)po * (NXX * NYY) + xi * NYY + y;
    float* lb = &lds[0];

    // drain preamble VMEM so the ladder below counts exactly
    asm volatile("s_waitcnt vmcnt(0)" ::: "memory");

    // dest: slot base + wv*256 floats (wave-uniform; HW adds lane*16B -> the
    // wave's row lands linearly at [R][0..255] of the slot).
#define STAGE(nn, slot)                                                        \
    __builtin_amdgcn_global_load_lds(                                          \
        (const __attribute__((address_space(1))) void*)(xs + (size_t)(nn) * nstr), \
        (__attribute__((address_space(3))) void*)(lb + ((slot) << 12) + (wv << 8)), \
        16, 0, 0)

    STAGE(0, 0);
    STAGE(1, 1);
    STAGE(2, 2);

    for (int n = 0; n < NPER; ++n) {
        // per-wave wait: own slot-n gl_lds retired (ladder: newer ops only).
        // steady state: after gl(n): gl(n+1),gl(n+2),st(n-3..n-1) = 5 newer.
        if      (n >= 3) asm volatile("s_waitcnt vmcnt(5)" ::: "memory");
        else if (n == 2) asm volatile("s_waitcnt vmcnt(4)" ::: "memory");
        else if (n == 1) asm volatile("s_waitcnt vmcnt(3)" ::: "memory");
        else             asm volatile("s_waitcnt vmcnt(2)" ::: "memory");
        __builtin_amdgcn_s_barrier();            // all 16 waves' rows ready
        asm volatile("" ::: "memory");           // pin ds_reads below barrier

        // stage n+3 now: its slot (n+3)&3 == (n-1)&3 was consumed by every
        // wave's compute(n-1), which precedes barrier(n) in program order.
        const int ns3 = (n + 3 < NPER) ? (n + 3) : (NPER - 1);
        STAGE(ns3, ns3 & 3);                     // clamped tail: idempotent bytes

        // slot layout: rows R=4c+{0,1,2,3} = {d0r0,d0r1,d1r0,d1r1} of channel c;
        // float2 row base = R*128; col pair y -> {a,e}/{b,f}.
        const float2* b2 = (const float2*)(lb + ((n & 3) << 12));
        float acc = bv;
#pragma unroll
        for (int c = 0; c < CIN; ++c) {
            const float2 ae0 = b2[c * 512 +       y];   // d0 row0 {a,e}
            const float2 bf0 = b2[c * 512 + 128 + y];   // d0 row1 {b,f}
            const float2 ae1 = b2[c * 512 + 256 + y];   // d1 row0 {a,e}
            const float2 bf1 = b2[c * 512 + 384 + y];   // d1 row1 {b,f}
            const float a0 = ae0.x, e0 = ae0.y, b0 = bf0.x, f0 = bf0.y;
            const float a1 = ae1.x, e1 = ae1.y, b1 = bf1.x, f1 = bf1.y;
            const float ef00 = e0*f0, ef01 = e0*f1, ef10 = e1*f0, ef11 = e1*f1;
            const float ab00 = a0*b0, ab01 = a0*b1, ab10 = a1*b0, ab11 = a1*b1;
            const float* wq = wr[c];
            float t;
            t = ef00*wq[ 0] + ef01*wq[ 1] + ef10*wq[ 2] + ef11*wq[ 3];  acc += ab00 * t;
            t = ef00*wq[ 4] + ef01*wq[ 5] + ef10*wq[ 6] + ef11*wq[ 7];  acc += ab01 * t;
            t = ef00*wq[ 8] + ef01*wq[ 9] + ef10*wq[10] + ef11*wq[11];  acc += ab10 * t;
            t = ef00*wq[12] + ef01*wq[13] + ef10*wq[14] + ef11*wq[15];  acc += ab11 * t;
        }
        ob[(size_t)n * ostr] = acc;              // 64 consecutive floats/wave
    }
#undef STAGE
}

extern "C" void kernel_launch(void* const* d_in, const int* in_sizes, int n_in,
                              void* d_out, int out_size, void* d_ws, size_t ws_size,
                              hipStream_t stream) {
    const float* x    = (const float*)d_in[0];
    const float* w    = (const float*)d_in[1];
    const float* bias = (const float*)d_in[2];
    float* out = (float*)d_out;

    const int grid = NXX * NSPLIT;               // 128*2 = 256 blocks, 1/CU
    ttn_kernel<<<grid, 1024, 0, stream>>>(x, w, bias, out);
}

// Round 10
// 242.734 us; speedup vs baseline: 1.0063x; 1.0063x over previous
//
#include <hip/hip_runtime.h>

// x: (64, 4, 2, 256, 256) f32 ; tensors: (4,4,128,128,2,2,2,2,2) f32 ;
// bias: (4,128,128,2) f32 ; out: (64,4,2,128,128) f32
// sx=sy=256 even -> ix1=2x+1, iy1=2y+1 (clamp inert).
#define NUMN 64
#define CIN 4
#define COUT 4
#define SX 256
#define SY 256
#define NXX 128
#define NYY 128
#define NSPLIT 2
#define NPER (NUMN / NSPLIT)
#define PLANE (SX * SY)
#define SLOTF 4096                   // floats per ring slot: 16 rows x 256
#define NSLOT 8                      // R14: ring depth 8 (was 4)

// R14: DEPTH test. R13 post-mortem: contiguous 1KB-row staging cleaned the
// fetch (FETCH 104->83.6MB) yet time didn't move; R13 moved FEWER bytes than
// R12 and was slower -> NOT bandwidth-bound. The invariant across all
// prefetched variants is per-iteration time ~2.7us = (loaded memory latency)
// / (depth 3). Little's law at 48KB/CU in flight and 1.4TB/s implies ~8.6us
// loaded latency -- self-consistent: we are LATENCY/DEPTH-limited with deep
// memory queues, not service-rate-limited. Decisive test: depth 3 -> 7
// (8-slot ring, 128KB static LDS -- m201 precedent). If T_iter = L/depth,
// dur drops ~40%; if flat, the 1.4TB/s pattern-ceiling theory wins instead.
// vmcnt ladder (stores share the queue, in-order): at wait(n) the ops newer
// than gl(n) are 6 gl + min(n,7) st -> vmcnt(min(6+n,13)); counted, never 0.
__global__ __launch_bounds__(1024, 1)
void ttn_kernel(const float* __restrict__ x, const float* __restrict__ w,
                const float* __restrict__ bias, float* __restrict__ out)
{
    __shared__ float lds[NSLOT * SLOTF];         // 8-slot ring, 128 KB

    const int bid = blockIdx.x;
    const int xi = bid % NXX;
    const int ns = bid / NXX;                    // 0..NSPLIT-1

    const int tid = threadIdx.x;                 // 0..1023
    const int wv  = tid >> 6;                    // wave 0..15 == row R it stages
    const int l   = tid & 63;
    const int po  = tid >> 7;                    // 0..7
    const int p   = po >> 1;
    const int o   = po & 1;
    const int y   = tid & 127;                   // 0..127 (full NYY)

    // ---- weight preamble: wr[c][q], q = 8i+4j+2k+l (float4 loads) ----
    float wr[CIN][16];
#pragma unroll
    for (int c = 0; c < CIN; ++c) {
        const float4* wp4 = (const float4*)(w +
            ((size_t)(((c * COUT + p) * NXX + xi) * NYY + y)) * 32);
#pragma unroll
        for (int j = 0; j < 8; ++j) {
            const float4 v = wp4[j];
            wr[c][2 * j]     = o ? v.y : v.x;
            wr[c][2 * j + 1] = o ? v.w : v.z;
        }
    }
    const float bv = bias[(((p * NXX + xi) * NYY + y) * 2) + o];

    const size_t nstr = (size_t)CIN * 2 * PLANE;
    const size_t ostr = (size_t)COUT * 2 * NXX * NYY;

    // staging: wave wv stages row R=wv = (c*2+d)*2 + r: plane cd=wv>>1,
    // x-row 2xi+(wv&1), ALL 256 cols. lane l reads floats 4l..4l+3 (16B),
    // so the wave's 64 lanes read one sequential 1KB row.
    const float* xs = x + (size_t)(ns * NPER) * nstr
                        + (size_t)(wv >> 1) * PLANE
                        + (size_t)(2 * xi + (wv & 1)) * SY + 4 * l;
    float* ob = out + (size_t)(ns * NPER) * ostr
                    + (size_t)po * (NXX * NYY) + xi * NYY + y;
    float* lb = &lds[0];

    // drain preamble VMEM so the vmcnt ladder below counts exactly
    asm volatile("s_waitcnt vmcnt(0)" ::: "memory");

    // dest: slot base + wv*256 floats (wave-uniform; HW adds lane*16B -> the
    // wave's row lands linearly at [R][0..255] of the slot).
#define STAGE(nn, slot)                                                        \
    __builtin_amdgcn_global_load_lds(                                          \
        (const __attribute__((address_space(1))) void*)(xs + (size_t)(nn) * nstr), \
        (__attribute__((address_space(3))) void*)(lb + ((slot) << 12) + (wv << 8)), \
        16, 0, 0)

#pragma unroll
    for (int k = 0; k < NSLOT - 1; ++k)          // prologue: slots 0..6
        STAGE(k, k);

    for (int n = 0; n < NPER; ++n) {
        // per-wave wait: own slot-n gl_lds retired. newer ops = 6 gl +
        // min(n,7) stores -> vmcnt(min(6+n,13)). Counted, never drains to 0.
        if      (n >= 7) asm volatile("s_waitcnt vmcnt(13)" ::: "memory");
        else if (n == 6) asm volatile("s_waitcnt vmcnt(12)" ::: "memory");
        else if (n == 5) asm volatile("s_waitcnt vmcnt(11)" ::: "memory");
        else if (n == 4) asm volatile("s_waitcnt vmcnt(10)" ::: "memory");
        else if (n == 3) asm volatile("s_waitcnt vmcnt(9)"  ::: "memory");
        else if (n == 2) asm volatile("s_waitcnt vmcnt(8)"  ::: "memory");
        else if (n == 1) asm volatile("s_waitcnt vmcnt(7)"  ::: "memory");
        else             asm volatile("s_waitcnt vmcnt(6)"  ::: "memory");
        __builtin_amdgcn_s_barrier();            // all 16 waves' rows ready
        asm volatile("" ::: "memory");           // pin ds_reads below barrier

        // stage n+7 now: its slot (n+7)&7 == (n-1)&7 was consumed by every
        // wave's compute(n-1), which precedes barrier(n) in program order.
        const int ns7 = (n + 7 < NPER) ? (n + 7) : (NPER - 1);
        STAGE(ns7, ns7 & (NSLOT - 1));           // clamped tail: idempotent bytes

        // slot layout: rows R=4c+{0,1,2,3} = {d0r0,d0r1,d1r0,d1r1} of channel c;
        // float2 row base = R*128; col pair y -> {a,e}/{b,f}.
        const float2* b2 = (const float2*)(lb + ((n & (NSLOT - 1)) << 12));
        float acc = bv;
#pragma unroll
        for (int c = 0; c < CIN; ++c) {
            const float2 ae0 = b2[c * 512 +       y];   // d0 row0 {a,e}
            const float2 bf0 = b2[c * 512 + 128 + y];   // d0 row1 {b,f}
            const float2 ae1 = b2[c * 512 + 256 + y];   // d1 row0 {a,e}
            const float2 bf1 = b2[c * 512 + 384 + y];   // d1 row1 {b,f}
            const float a0 = ae0.x, e0 = ae0.y, b0 = bf0.x, f0 = bf0.y;
            const float a1 = ae1.x, e1 = ae1.y, b1 = bf1.x, f1 = bf1.y;
            const float ef00 = e0*f0, ef01 = e0*f1, ef10 = e1*f0, ef11 = e1*f1;
            const float ab00 = a0*b0, ab01 = a0*b1, ab10 = a1*b0, ab11 = a1*b1;
            const float* wq = wr[c];
            float t;
            t = ef00*wq[ 0] + ef01*wq[ 1] + ef10*wq[ 2] + ef11*wq[ 3];  acc += ab00 * t;
            t = ef00*wq[ 4] + ef01*wq[ 5] + ef10*wq[ 6] + ef11*wq[ 7];  acc += ab01 * t;
            t = ef00*wq[ 8] + ef01*wq[ 9] + ef10*wq[10] + ef11*wq[11];  acc += ab10 * t;
            t = ef00*wq[12] + ef01*wq[13] + ef10*wq[14] + ef11*wq[15];  acc += ab11 * t;
        }
        ob[(size_t)n * ostr] = acc;              // 64 consecutive floats/wave
    }
#undef STAGE
}

extern "C" void kernel_launch(void* const* d_in, const int* in_sizes, int n_in,
                              void* d_out, int out_size, void* d_ws, size_t ws_size,
                              hipStream_t stream) {
    const float* x    = (const float*)d_in[0];
    const float* w    = (const float*)d_in[1];
    const float* bias = (const float*)d_in[2];
    float* out = (float*)d_out;

    const int grid = NXX * NSPLIT;               // 128*2 = 256 blocks, 1/CU
    ttn_kernel<<<grid, 1024, 0, stream>>>(x, w, bias, out);
}